// Round 11
// baseline (282.433 us; speedup 1.0000x reference)
//
#include <hip/hip_runtime.h>
#include <hip/hip_bf16.h>

#define NUM_GRAPHS 64
#define NODES 256
#define EDGES 1024
#define NTOT (NUM_GRAPHS * NODES) /* 16384 */
#define DF 512
#define HF 1024
#define HP 256
#define NC 10
#define INF32 0xFFFFFFFFu

typedef short bf16x8 __attribute__((ext_vector_type(8)));
typedef unsigned short u16x8 __attribute__((ext_vector_type(8)));
typedef float f32x4 __attribute__((ext_vector_type(4)));

__device__ __forceinline__ unsigned short bf16r(float f) {
    __hip_bfloat16 h = __float2bfloat16(f);
    return *(unsigned short*)&h;
}
// monotone order-preserving encode for fp32 (bijection, works for +/-)
__device__ __forceinline__ unsigned encf(float x) {
    union { float f; unsigned u; } c; c.f = x;
    return (c.u & 0x80000000u) ? ~c.u : (c.u | 0x80000000u);
}

// ---- w1 (f32 [k][j]) -> w1f bf16 in MFMA B-fragment order -----------------
// w1f elem index: ((colgrp*16 + t)*16 + n16)*32 + k31, where col = colgrp*16
// + n16 (0..1023), k = t*32 + k31 (0..511). A wave's per-t fragment load
// (lanes: n16 = lane&15, quad = lane>>4, 8 elems) is then 1 KB contiguous.
__global__ __launch_bounds__(256) void k_cvt_frag(
    const float* __restrict__ w1, unsigned short* __restrict__ w1f)
{
    __shared__ float xsl[256 * 16];   // 16 KB: [kk][c] for this (cg, khalf)
    const int tid = threadIdx.x;
    const int cg = blockIdx.x >> 1;      // colgrp 0..63
    const int th = blockIdx.x & 1;       // k half: k in [th*256, th*256+256)
    const int c = tid & 15, kr = tid >> 4;

    for (int it = 0; it < 16; ++it) {
        int kk = it * 16 + kr;
        xsl[kk * 16 + c] = w1[(size_t)(th * 256 + kk) * HF + cg * 16 + c];
    }
    __syncthreads();

#pragma unroll
    for (int p = 0; p < 2; ++p) {
        int ch = tid + 256 * p;              // 512 chunks of 16 B
        int tt = ch >> 6;                    // local t 0..7
        int n16 = (ch >> 2) & 15;
        int quad = ch & 3;
        u16x8 v;
#pragma unroll
        for (int j = 0; j < 8; ++j)
            v[j] = bf16r(xsl[(tt * 32 + quad * 8 + j) * 16 + n16]);
        size_t off = ((size_t)(cg * 16 + th * 8 + tt) * 16 + n16) * 32 + quad * 8;
        *(u16x8*)(w1f + off) = v;
    }
}

// ------------- Stage 1 (MFMA): f = sigmoid(relu(x@W1+b1)@w2 + b2) ---------
// 512 blocks x 32 nodes, 512 threads (8 waves). Wave w owns cols
// [128w, 128w+128) as 8 subs of 16; B fragments read 1 KB-contiguous from
// w1f; x tile bf16 in LDS (pad 8 -> row stride 1040 B, 2-way banks = free).
#define XPAD 8
#define XROW (DF + XPAD)
__global__ __launch_bounds__(512) void k_fil_mfma(
    const float* __restrict__ x, const unsigned short* __restrict__ w1f,
    const float* __restrict__ b1, const float* __restrict__ w2,
    const float* __restrict__ b2, float* __restrict__ fout)
{
    __shared__ unsigned short xs[32 * XROW];  // 33.3 KB
    __shared__ float facc[32];
    const int tid = threadIdx.x;
    const int lane = tid & 63;
    const int wv = tid >> 6;          // wave 0..7
    const int l15 = lane & 15;
    const int quad = lane >> 4;       // 0..3
    const int n0 = blockIdx.x * 32;

    for (int c = tid; c < 32 * DF / 4; c += 512) {
        int n = c >> 7, k4 = (c & 127) << 2;
        float4 v = *(const float4*)(x + (size_t)(n0 + n) * DF + k4);
        unsigned short* d = &xs[n * XROW + k4];
        d[0] = bf16r(v.x); d[1] = bf16r(v.y); d[2] = bf16r(v.z); d[3] = bf16r(v.w);
    }
    if (tid < 32) facc[tid] = 0.f;
    __syncthreads();

    float s_[2][4] = {{0.f,0.f,0.f,0.f},{0.f,0.f,0.f,0.f}};

    for (int sub = 0; sub < 8; ++sub) {
        const int cg = wv * 8 + sub;               // colgrp
        const int col = cg * 16 + l15;
        f32x4 acc0 = {0.f,0.f,0.f,0.f}, acc1 = {0.f,0.f,0.f,0.f};
        const unsigned short* bp = w1f + (size_t)cg * 8192 + l15 * 32 + quad * 8;
        const unsigned short* a0p = &xs[l15 * XROW + quad * 8];
        const unsigned short* a1p = &xs[(16 + l15) * XROW + quad * 8];
#pragma unroll
        for (int t = 0; t < 16; ++t) {
            bf16x8 bfrag = *(const bf16x8*)(bp + t * 512);
            bf16x8 a0 = *(const bf16x8*)(a0p + t * 32);
            bf16x8 a1 = *(const bf16x8*)(a1p + t * 32);
            acc0 = __builtin_amdgcn_mfma_f32_16x16x32_bf16(a0, bfrag, acc0, 0, 0, 0);
            acc1 = __builtin_amdgcn_mfma_f32_16x16x32_bf16(a1, bfrag, acc1, 0, 0, 0);
        }
        const float b1c = b1[col], w2c = w2[col];
#pragma unroll
        for (int r = 0; r < 4; ++r) {
            float h0 = acc0[r] + b1c; h0 = h0 > 0.f ? h0 : 0.f; s_[0][r] = fmaf(h0, w2c, s_[0][r]);
            float h1 = acc1[r] + b1c; h1 = h1 > 0.f ? h1 : 0.f; s_[1][r] = fmaf(h1, w2c, s_[1][r]);
        }
    }
#pragma unroll
    for (int q = 0; q < 2; ++q)
#pragma unroll
        for (int r = 0; r < 4; ++r) {
            float v = s_[q][r];
            v += __shfl_xor(v, 1, 16);
            v += __shfl_xor(v, 2, 16);
            v += __shfl_xor(v, 4, 16);
            v += __shfl_xor(v, 8, 16);
            if (l15 == 0) atomicAdd(&facc[q * 16 + quad * 4 + r], v);
        }
    __syncthreads();
    if (tid < 32) {
        float z = facc[tid] + b2[0];
        fout[n0 + tid] = 1.f / (1.f + expf(-z));
    }
}

// ---------------- Stage 1 legacy (fp32 VALU) — ws_size fallback -----------
#define TN2 16
__global__ __launch_bounds__(256) void k_fil(
    const float* __restrict__ x, const float* __restrict__ w1,
    const float* __restrict__ b1, const float* __restrict__ w2,
    const float* __restrict__ b2, float* __restrict__ fout)
{
    __shared__ float xs[TN2][DF];
    __shared__ float part[256];
    const int tid = threadIdx.x;
    const int n0 = blockIdx.x * TN2;
    for (int c = tid; c < TN2 * DF / 4; c += 256) {
        int n = c >> 7, k4 = (c & 127) << 2;
        *(float4*)&xs[n][k4] = *(const float4*)(x + (size_t)(n0 + n) * DF + k4);
    }
    __syncthreads();
    float h[TN2][4];
#pragma unroll
    for (int n = 0; n < TN2; ++n)
#pragma unroll
        for (int q = 0; q < 4; ++q) h[n][q] = 0.f;
    for (int k = 0; k < DF; ++k) {
        float wr[4];
#pragma unroll
        for (int q = 0; q < 4; ++q) wr[q] = w1[(size_t)k * HF + tid + 256 * q];
#pragma unroll
        for (int n = 0; n < TN2; ++n) {
            float xv = xs[n][k];
#pragma unroll
            for (int q = 0; q < 4; ++q) h[n][q] = fmaf(xv, wr[q], h[n][q]);
        }
    }
    float b1r[4], w2r[4];
#pragma unroll
    for (int q = 0; q < 4; ++q) { b1r[q] = b1[tid + 256 * q]; w2r[q] = w2[tid + 256 * q]; }
    const float b2v = b2[0];
    for (int n = 0; n < TN2; ++n) {
        float s = 0.f;
#pragma unroll
        for (int q = 0; q < 4; ++q) {
            float hv = h[n][q] + b1r[q];
            s += (hv > 0.f ? hv : 0.f) * w2r[q];
        }
        part[tid] = s;
        __syncthreads();
        for (int off = 128; off > 0; off >>= 1) {
            if (tid < off) part[tid] += part[tid + off];
            __syncthreads();
        }
        if (tid == 0) fout[n0 + n] = 1.f / (1.f + expf(-(part[0] + b2v)));
        __syncthreads();
    }
}

// ------------- Stage 2: Boruvka MST filter + wave-parallel Kruskal --------
__global__ __launch_bounds__(256) void k_pers(
    const int* __restrict__ edges, const float* __restrict__ fbuf,
    float* __restrict__ dout /* [2][NTOT] */)
{
    const int bid = blockIdx.x;
    const int g = bid >> 1, sgn = bid & 1;
    const int tid = threadIdx.x;

    __shared__ float fv[NODES];
    __shared__ unsigned long long vkey[NODES];
    __shared__ int order_[NODES], rank_[NODES];
    __shared__ float fvr[NODES];
    __shared__ unsigned eks[EDGES];
    __shared__ int comp[NODES];
    __shared__ unsigned minE[NODES];
    __shared__ int nxt[NODES], par2[NODES];
    __shared__ unsigned char mstflag[EDGES];
    __shared__ int cnt;
    __shared__ unsigned mstK[NODES];
    __shared__ int par[NODES], dr[NODES], cmaxr[NODES];

    float f0 = fbuf[g * NODES + tid];
    fv[tid] = sgn ? -f0 : f0;
    vkey[tid] = ((unsigned long long)encf(fv[tid]) << 32) | (unsigned)tid;
    __syncthreads();

    // bitonic sort 256 vertex keys ascending
    for (int k = 2; k <= NODES; k <<= 1)
        for (int j = k >> 1; j > 0; j >>= 1) {
            int i = tid, ixj = i ^ j;
            if (ixj > i) {
                unsigned long long a = vkey[i], b = vkey[ixj];
                bool up = ((i & k) == 0);
                if ((a > b) == up) { vkey[i] = b; vkey[ixj] = a; }
            }
            __syncthreads();
        }

    int ov = (int)(unsigned)(vkey[tid] & 0xFFFFFFFFULL);
    order_[tid] = ov;
    rank_[ov] = tid;
    fvr[tid] = fv[ov];
    comp[tid] = tid;
    __syncthreads();

    // edge keys in rank domain; self-loops -> INF
#pragma unroll
    for (int q = 0; q < 4; ++q) {
        int e = tid + q * 256;
        int u = edges[2 * (g * EDGES + e)]     - g * NODES;
        int v = edges[2 * (g * EDGES + e) + 1] - g * NODES;
        if (u == v) { eks[e] = INF32; }
        else {
            int ra = rank_[u], rb = rank_[v];
            int rlo = ra < rb ? ra : rb, rhi = ra < rb ? rb : ra;
            eks[e] = ((unsigned)rhi << 18) | ((unsigned)e << 8) | (unsigned)rlo;
        }
        mstflag[e] = 0;
    }
    __syncthreads();

    // Boruvka: 8 rounds
    for (int round = 0; round < 8; ++round) {
        minE[tid] = INF32;
        __syncthreads();
#pragma unroll
        for (int q = 0; q < 4; ++q) {
            unsigned k = eks[tid + q * 256];
            if (k != INF32) {
                int rlo = (int)(k & 255u), rhi = (int)(k >> 18);
                int cu = comp[rlo], cv = comp[rhi];
                if (cu != cv) {
                    atomicMin(&minE[cu], k);
                    atomicMin(&minE[cv], k);
                }
            }
        }
        __syncthreads();
        {
            unsigned mk = minE[tid];
            int o = tid;
            if (mk != INF32) {
                int rlo = (int)(mk & 255u), rhi = (int)(mk >> 18);
                int cu = comp[rlo], cv = comp[rhi];
                o = (cu == tid) ? cv : cu;
                mstflag[(mk >> 8) & 0x3FFu] = 1;
            }
            nxt[tid] = o;
        }
        __syncthreads();
        {
            int o = nxt[tid];
            int p = o;
            if (nxt[o] == tid && tid < o) p = tid;
            par2[tid] = p;
        }
        __syncthreads();
        for (int j = 0; j < 8; ++j) {
            int p = par2[par2[tid]];
            __syncthreads();
            par2[tid] = p;
            __syncthreads();
        }
        comp[tid] = par2[comp[tid]];
        __syncthreads();
    }

    // collect MST edges (<=255)
    if (tid == 0) cnt = 0;
    __syncthreads();
#pragma unroll
    for (int q = 0; q < 4; ++q) {
        int e = tid + q * 256;
        if (mstflag[e]) {
            int p = atomicAdd(&cnt, 1);
            mstK[p] = eks[e];
        }
    }
    __syncthreads();
    if (tid >= cnt) mstK[tid] = INF32;
    __syncthreads();

    // bitonic sort 256 u32 MST keys ascending
    for (int k = 2; k <= NODES; k <<= 1)
        for (int j = k >> 1; j > 0; j >>= 1) {
            int i = tid, ixj = i ^ j;
            if (ixj > i) {
                unsigned a = mstK[i], b = mstK[ixj];
                bool up = ((i & k) == 0);
                if ((a > b) == up) { mstK[i] = b; mstK[ixj] = a; }
            }
            __syncthreads();
        }

    dr[tid] = -1; cmaxr[tid] = 0;
    __syncthreads();

    // wave-parallel Kruskal replay on sorted MST edges: comp flat in wave-0
    // registers (lane L holds vertices 4L..4L+3); roots via shfl (no LDS
    // latency); every MST edge merges distinct comps (forest property).
    if (tid < 64) {
        int comp0 = tid * 4, comp1 = tid * 4 + 1, comp2 = tid * 4 + 2, comp3 = tid * 4 + 3;
        unsigned k40 = mstK[tid], k41 = mstK[64 + tid],
                 k42 = mstK[128 + tid], k43 = mstK[192 + tid];
        const int CNT = cnt;
        for (int s = 0; s < CNT; ++s) {
            int slot = s >> 6, sl = s & 63;
            unsigned kk;
            if (slot == 0)      kk = (unsigned)__shfl((int)k40, sl, 64);
            else if (slot == 1) kk = (unsigned)__shfl((int)k41, sl, 64);
            else if (slot == 2) kk = (unsigned)__shfl((int)k42, sl, 64);
            else                kk = (unsigned)__shfl((int)k43, sl, 64);
            int rlo = (int)(kk & 255u), rhi = (int)(kk >> 18);
            int la = rlo >> 2, sa = rlo & 3;
            int a0 = __shfl(comp0, la, 64), a1 = __shfl(comp1, la, 64);
            int a2 = __shfl(comp2, la, 64), a3 = __shfl(comp3, la, 64);
            int a = (sa == 0) ? a0 : ((sa == 1) ? a1 : ((sa == 2) ? a2 : a3));
            int lb = rhi >> 2, sb = rhi & 3;
            int b0 = __shfl(comp0, lb, 64), b1_ = __shfl(comp1, lb, 64);
            int b2_ = __shfl(comp2, lb, 64), b3 = __shfl(comp3, lb, 64);
            int b = (sb == 0) ? b0 : ((sb == 1) ? b1_ : ((sb == 2) ? b2_ : b3));
            int elder = a < b ? a : b, young = a < b ? b : a;
            comp0 = (comp0 == young) ? elder : comp0;
            comp1 = (comp1 == young) ? elder : comp1;
            comp2 = (comp2 == young) ? elder : comp2;
            comp3 = (comp3 == young) ? elder : comp3;
            if (tid == 0) dr[young] = rhi;
        }
        par[tid * 4] = comp0; par[tid * 4 + 1] = comp1;
        par[tid * 4 + 2] = comp2; par[tid * 4 + 3] = comp3;
    }
    __syncthreads();

    // component max (extended persistence); par is flat (no chasing)
    int r = par[tid];
    atomicMax(&cmaxr[r], tid);
    __syncthreads();

    float dv = (dr[tid] >= 0) ? fvr[dr[tid]] : fvr[cmaxr[r]];
    dout[sgn * NTOT + g * NODES + order_[tid]] = dv;
}

// ------- Stage 3: per-pair MLPs + segment sum + linear head (fused) -------
__global__ __launch_bounds__(256) void k_head(
    const float* __restrict__ fbuf, const float* __restrict__ dbuf,
    const float* __restrict__ wp0, const float* __restrict__ bp0,
    const float* __restrict__ wp1, const float* __restrict__ bp1,
    const float* __restrict__ wh, const float* __restrict__ bh,
    float* __restrict__ out)
{
    const int g = blockIdx.x, tid = threadIdx.x;
    __shared__ float lf[NODES], l0[NODES], l1[NODES];
    __shared__ float sp0[NODES], sp1[NODES];
    lf[tid] = fbuf[g * NODES + tid];
    l0[tid] = dbuf[g * NODES + tid];
    l1[tid] = dbuf[NTOT + g * NODES + tid];
    __syncthreads();
    const float w00 = wp0[tid], w01 = wp0[HP + tid], bb0 = bp0[tid];
    const float w10 = wp1[tid], w11 = wp1[HP + tid], bb1 = bp1[tid];
    float s0 = 0.f, s1 = 0.f;
    for (int n = 0; n < NODES; ++n) {
        float f = lf[n], d0 = l0[n], d1 = l1[n];
        float a0 = fmaf(f, w00, fmaf(d0, w01, bb0));      // h0 = (f, d_sub)
        float a1 = fmaf(-d1, w10, fmaf(f, w11, bb1));     // h1 = (-d_sup, f)
        s0 += a0 > 0.f ? a0 : 0.f;
        s1 += a1 > 0.f ? a1 : 0.f;
    }
    sp0[tid] = s0; sp1[tid] = s1;
    __syncthreads();
    if (tid < NC) {
        float acc = bh[tid];
        for (int j = 0; j < HP; ++j)
            acc += sp0[j] * wh[j * NC + tid] + sp1[j] * wh[(HP + j) * NC + tid];
        out[g * NC + tid] = acc;   // f32 output (reference dtype)
    }
}

extern "C" void kernel_launch(void* const* d_in, const int* in_sizes, int n_in,
                              void* d_out, int out_size, void* d_ws, size_t ws_size,
                              hipStream_t stream)
{
    const float* x   = (const float*)d_in[0];
    const int*   edg = (const int*)d_in[1];
    const float* w1  = (const float*)d_in[3];
    const float* b1  = (const float*)d_in[4];
    const float* w2  = (const float*)d_in[5];
    const float* b2  = (const float*)d_in[6];
    const float* wp0 = (const float*)d_in[7];
    const float* bp0 = (const float*)d_in[8];
    const float* wp1 = (const float*)d_in[9];
    const float* bp1 = (const float*)d_in[10];
    const float* wh  = (const float*)d_in[11];
    const float* bh  = (const float*)d_in[12];

    float* fbuf = (float*)d_ws;                       // [NTOT] f32
    float* dbuf = fbuf + NTOT;                        // [2][NTOT] f32
    unsigned short* w1f = (unsigned short*)(dbuf + 2 * NTOT);  // 1 MB bf16

    const size_t WS_REQ = (size_t)NTOT * 4 + (size_t)2 * NTOT * 4
                        + (size_t)HF * DF * 2 + 256;

    if (ws_size >= WS_REQ) {
        k_cvt_frag<<<128, 256, 0, stream>>>(w1, w1f);
        k_fil_mfma<<<NTOT / 32, 512, 0, stream>>>(x, w1f, b1, w2, b2, fbuf);
    } else {
        k_fil     <<<NTOT / TN2, 256, 0, stream>>>(x, w1, b1, w2, b2, fbuf);
    }
    k_pers<<<NUM_GRAPHS * 2, 256, 0, stream>>>(edg, fbuf, dbuf);
    k_head<<<NUM_GRAPHS, 256, 0, stream>>>(fbuf, dbuf, wp0, bp0, wp1, bp1, wh, bh,
                                           (float*)d_out);
}

// Round 12
// 273.061 us; speedup vs baseline: 1.0343x; 1.0343x over previous
//
#include <hip/hip_runtime.h>
#include <hip/hip_bf16.h>

#define NUM_GRAPHS 64
#define NODES 256
#define EDGES 1024
#define NTOT (NUM_GRAPHS * NODES) /* 16384 */
#define DF 512
#define HF 1024
#define HP 256
#define NC 10
#define INF32 0xFFFFFFFFu

typedef short bf16x8 __attribute__((ext_vector_type(8)));
typedef unsigned short u16x8 __attribute__((ext_vector_type(8)));
typedef float f32x4 __attribute__((ext_vector_type(4)));

__device__ __forceinline__ unsigned short bf16r(float f) {
    __hip_bfloat16 h = __float2bfloat16(f);
    return *(unsigned short*)&h;
}
// monotone order-preserving encode for fp32 (bijection, works for +/-)
__device__ __forceinline__ unsigned encf(float x) {
    union { float f; unsigned u; } c; c.f = x;
    return (c.u & 0x80000000u) ? ~c.u : (c.u | 0x80000000u);
}

// ---- zero zacc (ws is poisoned each launch) ------------------------------
__global__ void k_zero(float* __restrict__ z) {
    z[blockIdx.x * 256 + threadIdx.x] = 0.f;
}

// ---- w1 (f32 [k][j]) -> w1f bf16 in MFMA B-fragment order ----------------
// w1f elem index: ((cg*16 + t)*16 + n16)*32 + quad*8 + j, col = cg*16+n16,
// k = t*32 + quad*8 + j. 256 blocks: (cg, kq) -> 16 cols x 128 k each.
__global__ __launch_bounds__(256) void k_cvt_frag(
    const float* __restrict__ w1, unsigned short* __restrict__ w1f)
{
    __shared__ float ls[128 * 16];   // [kk][c], 8 KB
    const int tid = threadIdx.x;
    const int cg = blockIdx.x >> 2, kq = blockIdx.x & 3;
    const int c = tid & 15, kr = tid >> 4;
#pragma unroll
    for (int it = 0; it < 8; ++it) {
        int kk = it * 16 + kr;
        ls[kk * 16 + c] = w1[(size_t)(kq * 128 + kk) * HF + cg * 16 + c];
    }
    __syncthreads();
    const int tt = tid >> 6, n16 = (tid >> 2) & 15, q = tid & 3;
    u16x8 v;
#pragma unroll
    for (int j = 0; j < 8; ++j)
        v[j] = bf16r(ls[(tt * 32 + q * 8 + j) * 16 + n16]);
    size_t off = ((size_t)(cg * 16 + kq * 4 + tt) * 16 + n16) * 32 + q * 8;
    *(u16x8*)(w1f + off) = v;
}

// ------------- Stage 1 (MFMA v2): z = relu(x@W1+b1)@w2 (pre-sigmoid) ------
// Block: 64 rows x 128 cols, 256 thr (4 waves). A fragment-packed in 64 KB
// LDS (conflict-free b128); B in 64 VGPRs per coltile; XCD swizzle:
// bid%8 == rowchunk%8 so the 8 colsplit blocks of a rowchunk share one L2.
__global__ __launch_bounds__(256) void k_fil_mfma(
    const float* __restrict__ x, const unsigned short* __restrict__ w1f,
    const float* __restrict__ b1, const float* __restrict__ w2,
    float* __restrict__ zacc)
{
    __shared__ unsigned short apk[4 * 16 * 16 * 4 * 8];  // 64 KB packed A
    const int tid = threadIdx.x;
    const int lane = tid & 63;
    const int wv = tid >> 6;            // wave 0..3
    const int l15 = lane & 15, quad = lane >> 4;
    const int cs = blockIdx.x >> 8;     // colsplit 0..7
    const int rc = blockIdx.x & 255;    // rowchunk (bid%8 == rc%8 -> XCD)
    const int r0 = rc * 64;

    // stage x (64 rows x 512 k) f32 -> bf16, fragment-packed
#pragma unroll
    for (int p = 0; p < 16; ++p) {
        int ch = tid + p * 256;                      // 4096 16B chunks
        int rt = ch >> 10, t = (ch >> 6) & 15, fl = (ch >> 2) & 15, q = ch & 3;
        const float* src = x + (size_t)(r0 + rt * 16 + fl) * DF + t * 32 + q * 8;
        float4 v0 = *(const float4*)src;
        float4 v1 = *(const float4*)(src + 4);
        u16x8 pk;
        pk[0] = bf16r(v0.x); pk[1] = bf16r(v0.y); pk[2] = bf16r(v0.z); pk[3] = bf16r(v0.w);
        pk[4] = bf16r(v1.x); pk[5] = bf16r(v1.y); pk[6] = bf16r(v1.z); pk[7] = bf16r(v1.w);
        *(u16x8*)(apk + (size_t)ch * 8) = pk;
    }
    __syncthreads();

#pragma unroll
    for (int cc = 0; cc < 2; ++cc) {
        const int ct = wv * 2 + cc;          // coltile 0..7
        const int cg = cs * 8 + ct;          // global colgroup 0..63
        const int col = cg * 16 + l15;
        bf16x8 Bf[16];
#pragma unroll
        for (int t = 0; t < 16; ++t)
            Bf[t] = *(const bf16x8*)(w1f + (size_t)cg * 8192 + t * 512 + l15 * 32 + quad * 8);
        const float b1c = b1[col], w2c = w2[col];
#pragma unroll
        for (int rt = 0; rt < 4; ++rt) {
            f32x4 acc = {0.f, 0.f, 0.f, 0.f};
            const unsigned short* ap = apk + ((((size_t)rt * 16) * 16 + l15) * 4 + quad) * 8;
#pragma unroll
            for (int t = 0; t < 16; ++t) {
                bf16x8 a = *(const bf16x8*)(ap + t * 512);
                acc = __builtin_amdgcn_mfma_f32_16x16x32_bf16(a, Bf[t], acc, 0, 0, 0);
            }
#pragma unroll
            for (int r = 0; r < 4; ++r) {
                float h = acc[r] + b1c; h = h > 0.f ? h : 0.f;
                float v = h * w2c;
                v += __shfl_xor(v, 1, 16);
                v += __shfl_xor(v, 2, 16);
                v += __shfl_xor(v, 4, 16);
                v += __shfl_xor(v, 8, 16);
                if (l15 == 0) atomicAdd(&zacc[r0 + rt * 16 + quad * 4 + r], v);
            }
        }
    }
}

// ---- sigmoid epilogue: f = sigmoid(z + b2) -------------------------------
__global__ void k_sig(const float* __restrict__ zacc, const float* __restrict__ b2,
                      float* __restrict__ fout) {
    int i = blockIdx.x * 256 + threadIdx.x;
    fout[i] = 1.f / (1.f + expf(-(zacc[i] + b2[0])));
}

// ---------------- Stage 1 legacy (fp32 VALU) — ws_size fallback -----------
#define TN2 16
__global__ __launch_bounds__(256) void k_fil(
    const float* __restrict__ x, const float* __restrict__ w1,
    const float* __restrict__ b1, const float* __restrict__ w2,
    const float* __restrict__ b2, float* __restrict__ fout)
{
    __shared__ float xs[TN2][DF];
    __shared__ float part[256];
    const int tid = threadIdx.x;
    const int n0 = blockIdx.x * TN2;
    for (int c = tid; c < TN2 * DF / 4; c += 256) {
        int n = c >> 7, k4 = (c & 127) << 2;
        *(float4*)&xs[n][k4] = *(const float4*)(x + (size_t)(n0 + n) * DF + k4);
    }
    __syncthreads();
    float h[TN2][4];
#pragma unroll
    for (int n = 0; n < TN2; ++n)
#pragma unroll
        for (int q = 0; q < 4; ++q) h[n][q] = 0.f;
    for (int k = 0; k < DF; ++k) {
        float wr[4];
#pragma unroll
        for (int q = 0; q < 4; ++q) wr[q] = w1[(size_t)k * HF + tid + 256 * q];
#pragma unroll
        for (int n = 0; n < TN2; ++n) {
            float xv = xs[n][k];
#pragma unroll
            for (int q = 0; q < 4; ++q) h[n][q] = fmaf(xv, wr[q], h[n][q]);
        }
    }
    float b1r[4], w2r[4];
#pragma unroll
    for (int q = 0; q < 4; ++q) { b1r[q] = b1[tid + 256 * q]; w2r[q] = w2[tid + 256 * q]; }
    const float b2v = b2[0];
    for (int n = 0; n < TN2; ++n) {
        float s = 0.f;
#pragma unroll
        for (int q = 0; q < 4; ++q) {
            float hv = h[n][q] + b1r[q];
            s += (hv > 0.f ? hv : 0.f) * w2r[q];
        }
        part[tid] = s;
        __syncthreads();
        for (int off = 128; off > 0; off >>= 1) {
            if (tid < off) part[tid] += part[tid + off];
            __syncthreads();
        }
        if (tid == 0) fout[n0 + n] = 1.f / (1.f + expf(-(part[0] + b2v)));
        __syncthreads();
    }
}

// ------------- Stage 2: Boruvka MST filter + serial Kruskal replay --------
// Counting-rank sorts (keys unique), early-exit Boruvka, serial replay (R10).
__global__ __launch_bounds__(256) void k_pers(
    const int* __restrict__ edges, const float* __restrict__ fbuf,
    float* __restrict__ dout /* [2][NTOT] */)
{
    const int bid = blockIdx.x;
    const int g = bid >> 1, sgn = bid & 1;
    const int tid = threadIdx.x;

    __shared__ float fv[NODES];
    __shared__ unsigned long long vkey[NODES];
    __shared__ int order_[NODES], rank_[NODES];
    __shared__ float fvr[NODES];
    __shared__ unsigned eks[EDGES];
    __shared__ int comp[NODES];
    __shared__ unsigned minE[NODES];
    __shared__ int nxt[NODES], par2[NODES];
    __shared__ unsigned char mstflag[EDGES];
    __shared__ int cnt, chg;
    __shared__ unsigned mstK[NODES], srt[NODES];
    __shared__ int par[NODES], dr[NODES], cmaxr[NODES];

    float f0 = fbuf[g * NODES + tid];
    fv[tid] = sgn ? -f0 : f0;
    unsigned long long myk = ((unsigned long long)encf(fv[tid]) << 32) | (unsigned)tid;
    vkey[tid] = myk;
    srt[tid] = INF32; dr[tid] = -1; cmaxr[tid] = 0; par[tid] = tid;
    __syncthreads();

    // counting rank (keys unique): rank = #{j : key[j] < mine}; no barriers
    int rk = 0;
#pragma unroll 8
    for (int j = 0; j < NODES; ++j) rk += (vkey[j] < myk) ? 1 : 0;
    order_[rk] = tid;
    rank_[tid] = rk;
    fvr[rk] = fv[tid];
    comp[tid] = tid;
    __syncthreads();

    // edge keys in rank domain; self-loops -> INF
#pragma unroll
    for (int q = 0; q < 4; ++q) {
        int e = tid + q * 256;
        int u = edges[2 * (g * EDGES + e)]     - g * NODES;
        int v = edges[2 * (g * EDGES + e) + 1] - g * NODES;
        if (u == v) { eks[e] = INF32; }
        else {
            int ra = rank_[u], rb = rank_[v];
            int rlo = ra < rb ? ra : rb, rhi = ra < rb ? rb : ra;
            eks[e] = ((unsigned)rhi << 18) | ((unsigned)e << 8) | (unsigned)rlo;
        }
        mstflag[e] = 0;
    }
    __syncthreads();

    // Boruvka with early exit (typically ~5 rounds)
    for (int round = 0; round < 8; ++round) {
        minE[tid] = INF32;
        if (tid == 0) chg = 0;
        __syncthreads();
#pragma unroll
        for (int q = 0; q < 4; ++q) {
            unsigned k = eks[tid + q * 256];
            if (k != INF32) {
                int rlo = (int)(k & 255u), rhi = (int)(k >> 18);
                int cu = comp[rlo], cv = comp[rhi];
                if (cu != cv) {
                    atomicMin(&minE[cu], k);
                    atomicMin(&minE[cv], k);
                }
            }
        }
        __syncthreads();
        {
            unsigned mk = minE[tid];
            int o = tid;
            if (mk != INF32) {
                int rlo = (int)(mk & 255u), rhi = (int)(mk >> 18);
                int cu = comp[rlo], cv = comp[rhi];
                o = (cu == tid) ? cv : cu;
                mstflag[(mk >> 8) & 0x3FFu] = 1;
                chg = 1;
            }
            nxt[tid] = o;
        }
        __syncthreads();
        if (!chg) break;
        {
            int o = nxt[tid];
            int p = o;
            if (nxt[o] == tid && tid < o) p = tid;
            par2[tid] = p;
        }
        __syncthreads();
        for (int j = 0; j < 8; ++j) {
            int p = par2[par2[tid]];
            __syncthreads();
            par2[tid] = p;
            __syncthreads();
        }
        comp[tid] = par2[comp[tid]];
        __syncthreads();
    }

    // collect MST edges (<=255)
    if (tid == 0) cnt = 0;
    __syncthreads();
#pragma unroll
    for (int q = 0; q < 4; ++q) {
        int e = tid + q * 256;
        if (mstflag[e]) {
            int p = atomicAdd(&cnt, 1);
            mstK[p] = eks[e];
        }
    }
    __syncthreads();
    if (tid >= cnt) mstK[tid] = INF32;
    __syncthreads();

    // counting sort of MST keys (unique among valid)
    unsigned myk2 = mstK[tid];
    if (myk2 != INF32) {
        int pos = 0;
#pragma unroll 8
        for (int j = 0; j < NODES; ++j) pos += (mstK[j] < myk2) ? 1 : 0;
        srt[pos] = myk2;
    }
    __syncthreads();

    // serial Kruskal replay (rank domain: elder = smaller rank, death=fvr[rhi])
    if (tid == 0) {
        for (int s = 0; s < NODES; ++s) {
            unsigned k = srt[s];
            if (k == INF32) break;
            int rlo = (int)(k & 255u), rhi = (int)(k >> 18);
            int a = rlo; while (par[a] != a) { par[a] = par[par[a]]; a = par[a]; }
            int b = rhi; while (par[b] != b) { par[b] = par[par[b]]; b = par[b]; }
            if (a != b) {
                int elder = a < b ? a : b, young = a < b ? b : a;
                par[young] = elder;
                dr[young] = rhi;
            }
        }
    }
    __syncthreads();

    // component max (extended persistence)
    int r = tid;
    while (par[r] != r) r = par[r];
    atomicMax(&cmaxr[r], tid);
    __syncthreads();

    float dv = (dr[tid] >= 0) ? fvr[dr[tid]] : fvr[cmaxr[r]];
    dout[sgn * NTOT + g * NODES + order_[tid]] = dv;
}

// ------- Stage 3: per-pair MLPs + segment sum + linear head (fused) -------
__global__ __launch_bounds__(256) void k_head(
    const float* __restrict__ fbuf, const float* __restrict__ dbuf,
    const float* __restrict__ wp0, const float* __restrict__ bp0,
    const float* __restrict__ wp1, const float* __restrict__ bp1,
    const float* __restrict__ wh, const float* __restrict__ bh,
    float* __restrict__ out)
{
    const int g = blockIdx.x, tid = threadIdx.x;
    __shared__ float lf[NODES], l0[NODES], l1[NODES];
    __shared__ float sp0[NODES], sp1[NODES];
    lf[tid] = fbuf[g * NODES + tid];
    l0[tid] = dbuf[g * NODES + tid];
    l1[tid] = dbuf[NTOT + g * NODES + tid];
    __syncthreads();
    const float w00 = wp0[tid], w01 = wp0[HP + tid], bb0 = bp0[tid];
    const float w10 = wp1[tid], w11 = wp1[HP + tid], bb1 = bp1[tid];
    float s0 = 0.f, s1 = 0.f;
    for (int n = 0; n < NODES; ++n) {
        float f = lf[n], d0 = l0[n], d1 = l1[n];
        float a0 = fmaf(f, w00, fmaf(d0, w01, bb0));      // h0 = (f, d_sub)
        float a1 = fmaf(-d1, w10, fmaf(f, w11, bb1));     // h1 = (-d_sup, f)
        s0 += a0 > 0.f ? a0 : 0.f;
        s1 += a1 > 0.f ? a1 : 0.f;
    }
    sp0[tid] = s0; sp1[tid] = s1;
    __syncthreads();
    if (tid < NC) {
        float acc = bh[tid];
        for (int j = 0; j < HP; ++j)
            acc += sp0[j] * wh[j * NC + tid] + sp1[j] * wh[(HP + j) * NC + tid];
        out[g * NC + tid] = acc;   // f32 output (reference dtype)
    }
}

extern "C" void kernel_launch(void* const* d_in, const int* in_sizes, int n_in,
                              void* d_out, int out_size, void* d_ws, size_t ws_size,
                              hipStream_t stream)
{
    const float* x   = (const float*)d_in[0];
    const int*   edg = (const int*)d_in[1];
    const float* w1  = (const float*)d_in[3];
    const float* b1  = (const float*)d_in[4];
    const float* w2  = (const float*)d_in[5];
    const float* b2  = (const float*)d_in[6];
    const float* wp0 = (const float*)d_in[7];
    const float* bp0 = (const float*)d_in[8];
    const float* wp1 = (const float*)d_in[9];
    const float* bp1 = (const float*)d_in[10];
    const float* wh  = (const float*)d_in[11];
    const float* bh  = (const float*)d_in[12];

    float* zacc = (float*)d_ws;                       // [NTOT] f32
    float* fbuf = zacc + NTOT;                        // [NTOT] f32
    float* dbuf = fbuf + NTOT;                        // [2][NTOT] f32
    unsigned short* w1f = (unsigned short*)(dbuf + 2 * NTOT);  // 1 MB bf16

    const size_t WS_REQ = (size_t)4 * NTOT * 4 + (size_t)HF * DF * 2 + 256;

    if (ws_size >= WS_REQ) {
        k_zero    <<<NTOT / 256, 256, 0, stream>>>(zacc);
        k_cvt_frag<<<256, 256, 0, stream>>>(w1, w1f);
        k_fil_mfma<<<2048, 256, 0, stream>>>(x, w1f, b1, w2, zacc);
        k_sig     <<<NTOT / 256, 256, 0, stream>>>(zacc, b2, fbuf);
    } else {
        k_fil     <<<NTOT / TN2, 256, 0, stream>>>(x, w1, b1, w2, b2, fbuf);
    }
    k_pers<<<NUM_GRAPHS * 2, 256, 0, stream>>>(edg, fbuf, dbuf);
    k_head<<<NUM_GRAPHS, 256, 0, stream>>>(fbuf, dbuf, wp0, bp0, wp1, bp1, wh, bh,
                                           (float*)d_out);
}

// Round 13
// 258.375 us; speedup vs baseline: 1.0931x; 1.0568x over previous
//
#include <hip/hip_runtime.h>
#include <hip/hip_bf16.h>

#define NUM_GRAPHS 64
#define NODES 256
#define EDGES 1024
#define NTOT (NUM_GRAPHS * NODES) /* 16384 */
#define DF 512
#define HF 1024
#define HP 256
#define NC 10
#define INF32 0xFFFFFFFFu

typedef short bf16x8 __attribute__((ext_vector_type(8)));
typedef unsigned short u16x8 __attribute__((ext_vector_type(8)));
typedef float f32x4 __attribute__((ext_vector_type(4)));

__device__ __forceinline__ unsigned short bf16r(float f) {
    __hip_bfloat16 h = __float2bfloat16(f);
    return *(unsigned short*)&h;
}
// monotone order-preserving encode for fp32 (bijection, works for +/-)
__device__ __forceinline__ unsigned encf(float x) {
    union { float f; unsigned u; } c; c.f = x;
    return (c.u & 0x80000000u) ? ~c.u : (c.u | 0x80000000u);
}

// ---- w1 (f32 [k][j]) -> w1f bf16 in MFMA B-fragment order; zero zbuf -----
// w1f elem index: ((cg*16 + t)*16 + n16)*32 + quad*8 + j, col = cg*16+n16,
// k = t*32 + quad*8 + j. 256 blocks: (cg, kq) -> 16 cols x 128 k each.
__global__ __launch_bounds__(256) void k_cvt_frag(
    const float* __restrict__ w1, unsigned short* __restrict__ w1f,
    float* __restrict__ zbuf)
{
    __shared__ float ls[128 * 16];   // [kk][c], 8 KB
    const int tid = threadIdx.x;
    if (tid < 64) zbuf[blockIdx.x * 64 + tid] = 0.f;   // piggyback zero
    const int cg = blockIdx.x >> 2, kq = blockIdx.x & 3;
    const int c = tid & 15, kr = tid >> 4;
#pragma unroll
    for (int it = 0; it < 8; ++it) {
        int kk = it * 16 + kr;
        ls[kk * 16 + c] = w1[(size_t)(kq * 128 + kk) * HF + cg * 16 + c];
    }
    __syncthreads();
    const int tt = tid >> 6, n16 = (tid >> 2) & 15, q = tid & 3;
    u16x8 v;
#pragma unroll
    for (int j = 0; j < 8; ++j)
        v[j] = bf16r(ls[(tt * 32 + q * 8 + j) * 16 + n16]);
    size_t off = ((size_t)(cg * 16 + kq * 4 + tt) * 16 + n16) * 32 + q * 8;
    *(u16x8*)(w1f + off) = v;
}

// ------- Stage 1 (MFMA v3): zbuf += relu(x@W1+b1)@w2 (pre-b2/sigmoid) -----
// 256 blocks x 64 rows x ALL 1024 cols. A tile 64 KB LDS, loaded ONCE per
// wave into registers (rt-pair passes, 128 VGPR); B streamed 1KB-contiguous
// from w1f (L2-resident per XCD); 4 independent MFMA chains (ILP-4);
// epilogue in registers, 256 global atomics/block.
__global__ __launch_bounds__(256, 1) void k_fil_mfma(
    const float* __restrict__ x, const unsigned short* __restrict__ w1f,
    const float* __restrict__ b1, const float* __restrict__ w2,
    float* __restrict__ zbuf)
{
    __shared__ unsigned short apk[64 * 512];  // 64 KB packed A
    const int tid = threadIdx.x;
    const int lane = tid & 63;
    const int wv = tid >> 6;            // wave 0..3
    const int l15 = lane & 15, quad = lane >> 4;
    const int r0 = blockIdx.x * 64;

    // stage x (64 rows x 512 k) f32 -> bf16, fragment-packed
#pragma unroll
    for (int p = 0; p < 16; ++p) {
        int ch = tid + p * 256;                      // 4096 16B chunks
        int rt = ch >> 10, t = (ch >> 6) & 15, fl = (ch >> 2) & 15, q = ch & 3;
        const float* src = x + (size_t)(r0 + rt * 16 + fl) * DF + t * 32 + q * 8;
        float4 v0 = *(const float4*)src;
        float4 v1 = *(const float4*)(src + 4);
        u16x8 pk;
        pk[0] = bf16r(v0.x); pk[1] = bf16r(v0.y); pk[2] = bf16r(v0.z); pk[3] = bf16r(v0.w);
        pk[4] = bf16r(v1.x); pk[5] = bf16r(v1.y); pk[6] = bf16r(v1.z); pk[7] = bf16r(v1.w);
        *(u16x8*)(apk + (size_t)ch * 8) = pk;
    }
    __syncthreads();

    float s_[4][4];
#pragma unroll
    for (int a = 0; a < 4; ++a)
#pragma unroll
        for (int b = 0; b < 4; ++b) s_[a][b] = 0.f;

#pragma unroll
    for (int pass = 0; pass < 2; ++pass) {
        const int rtA = pass * 2, rtB = pass * 2 + 1;
        bf16x8 Ar0[16], Ar1[16];
#pragma unroll
        for (int t = 0; t < 16; ++t) {
            Ar0[t] = *(const bf16x8*)(apk + rtA * 8192 + t * 512 + l15 * 32 + quad * 8);
            Ar1[t] = *(const bf16x8*)(apk + rtB * 8192 + t * 512 + l15 * 32 + quad * 8);
        }
#pragma unroll 2
        for (int i = 0; i < 16; ++i) {
            const int cg = wv + 4 * i;              // colgroup 0..63
            const int col = cg * 16 + l15;
            const unsigned short* bp = w1f + (size_t)cg * 8192 + l15 * 32 + quad * 8;
            bf16x8 Bf[16];
#pragma unroll
            for (int t = 0; t < 16; ++t)
                Bf[t] = *(const bf16x8*)(bp + t * 512);
            f32x4 aA0 = {0.f,0.f,0.f,0.f}, aA1 = {0.f,0.f,0.f,0.f};
            f32x4 aB0 = {0.f,0.f,0.f,0.f}, aB1 = {0.f,0.f,0.f,0.f};
#pragma unroll
            for (int t = 0; t < 8; ++t) {
                aA0 = __builtin_amdgcn_mfma_f32_16x16x32_bf16(Ar0[t], Bf[t], aA0, 0, 0, 0);
                aB0 = __builtin_amdgcn_mfma_f32_16x16x32_bf16(Ar1[t], Bf[t], aB0, 0, 0, 0);
                aA1 = __builtin_amdgcn_mfma_f32_16x16x32_bf16(Ar0[t + 8], Bf[t + 8], aA1, 0, 0, 0);
                aB1 = __builtin_amdgcn_mfma_f32_16x16x32_bf16(Ar1[t + 8], Bf[t + 8], aB1, 0, 0, 0);
            }
            const float b1c = b1[col], w2c = w2[col];
#pragma unroll
            for (int r = 0; r < 4; ++r) {
                float hA = (aA0[r] + aA1[r]) + b1c; hA = hA > 0.f ? hA : 0.f;
                s_[rtA][r] = fmaf(hA, w2c, s_[rtA][r]);
                float hB = (aB0[r] + aB1[r]) + b1c; hB = hB > 0.f ? hB : 0.f;
                s_[rtB][r] = fmaf(hB, w2c, s_[rtB][r]);
            }
        }
    }

    // reduce over the 16 col-lanes per quad; one global atomic per (rt,r,quad)
#pragma unroll
    for (int rt = 0; rt < 4; ++rt)
#pragma unroll
        for (int r = 0; r < 4; ++r) {
            float v = s_[rt][r];
            v += __shfl_xor(v, 1, 16);
            v += __shfl_xor(v, 2, 16);
            v += __shfl_xor(v, 4, 16);
            v += __shfl_xor(v, 8, 16);
            if (l15 == 0) atomicAdd(&zbuf[r0 + rt * 16 + quad * 4 + r], v);
        }
}

// ---------------- Stage 1 legacy (fp32 VALU) — ws_size fallback -----------
// Writes PRE-b2/sigmoid z (consumers apply sigmoid(z+b2)).
#define TN2 16
__global__ __launch_bounds__(256) void k_fil(
    const float* __restrict__ x, const float* __restrict__ w1,
    const float* __restrict__ b1, const float* __restrict__ w2,
    float* __restrict__ zout)
{
    __shared__ float xs[TN2][DF];
    __shared__ float part[256];
    const int tid = threadIdx.x;
    const int n0 = blockIdx.x * TN2;
    for (int c = tid; c < TN2 * DF / 4; c += 256) {
        int n = c >> 7, k4 = (c & 127) << 2;
        *(float4*)&xs[n][k4] = *(const float4*)(x + (size_t)(n0 + n) * DF + k4);
    }
    __syncthreads();
    float h[TN2][4];
#pragma unroll
    for (int n = 0; n < TN2; ++n)
#pragma unroll
        for (int q = 0; q < 4; ++q) h[n][q] = 0.f;
    for (int k = 0; k < DF; ++k) {
        float wr[4];
#pragma unroll
        for (int q = 0; q < 4; ++q) wr[q] = w1[(size_t)k * HF + tid + 256 * q];
#pragma unroll
        for (int n = 0; n < TN2; ++n) {
            float xv = xs[n][k];
#pragma unroll
            for (int q = 0; q < 4; ++q) h[n][q] = fmaf(xv, wr[q], h[n][q]);
        }
    }
    float b1r[4], w2r[4];
#pragma unroll
    for (int q = 0; q < 4; ++q) { b1r[q] = b1[tid + 256 * q]; w2r[q] = w2[tid + 256 * q]; }
    for (int n = 0; n < TN2; ++n) {
        float s = 0.f;
#pragma unroll
        for (int q = 0; q < 4; ++q) {
            float hv = h[n][q] + b1r[q];
            s += (hv > 0.f ? hv : 0.f) * w2r[q];
        }
        part[tid] = s;
        __syncthreads();
        for (int off = 128; off > 0; off >>= 1) {
            if (tid < off) part[tid] += part[tid + off];
            __syncthreads();
        }
        if (tid == 0) zout[n0 + n] = part[0];
        __syncthreads();
    }
}

// ------------- Stage 2: Boruvka MST filter + serial Kruskal replay --------
// f = sigmoid(z + b2) computed inline (monotone; values used for deaths).
__global__ __launch_bounds__(256) void k_pers(
    const int* __restrict__ edges, const float* __restrict__ zbuf,
    const float* __restrict__ b2, float* __restrict__ dout /* [2][NTOT] */)
{
    const int bid = blockIdx.x;
    const int g = bid >> 1, sgn = bid & 1;
    const int tid = threadIdx.x;

    __shared__ float fv[NODES];
    __shared__ unsigned long long vkey[NODES];
    __shared__ int order_[NODES], rank_[NODES];
    __shared__ float fvr[NODES];
    __shared__ unsigned eks[EDGES];
    __shared__ int comp[NODES];
    __shared__ unsigned minE[NODES];
    __shared__ int nxt[NODES], par2[NODES];
    __shared__ unsigned char mstflag[EDGES];
    __shared__ int cnt, chg;
    __shared__ unsigned mstK[NODES], srt[NODES];
    __shared__ int par[NODES], dr[NODES], cmaxr[NODES];

    float z0 = zbuf[g * NODES + tid];
    float f0 = 1.f / (1.f + expf(-(z0 + b2[0])));
    fv[tid] = sgn ? -f0 : f0;
    unsigned long long myk = ((unsigned long long)encf(fv[tid]) << 32) | (unsigned)tid;
    vkey[tid] = myk;
    srt[tid] = INF32; dr[tid] = -1; cmaxr[tid] = 0; par[tid] = tid;
    __syncthreads();

    // counting rank (keys unique): rank = #{j : key[j] < mine}
    int rk = 0;
#pragma unroll 8
    for (int j = 0; j < NODES; ++j) rk += (vkey[j] < myk) ? 1 : 0;
    order_[rk] = tid;
    rank_[tid] = rk;
    fvr[rk] = fv[tid];
    comp[tid] = tid;
    __syncthreads();

    // edge keys in rank domain; self-loops -> INF
#pragma unroll
    for (int q = 0; q < 4; ++q) {
        int e = tid + q * 256;
        int u = edges[2 * (g * EDGES + e)]     - g * NODES;
        int v = edges[2 * (g * EDGES + e) + 1] - g * NODES;
        if (u == v) { eks[e] = INF32; }
        else {
            int ra = rank_[u], rb = rank_[v];
            int rlo = ra < rb ? ra : rb, rhi = ra < rb ? rb : ra;
            eks[e] = ((unsigned)rhi << 18) | ((unsigned)e << 8) | (unsigned)rlo;
        }
        mstflag[e] = 0;
    }
    __syncthreads();

    // Boruvka with early exit
    for (int round = 0; round < 8; ++round) {
        minE[tid] = INF32;
        if (tid == 0) chg = 0;
        __syncthreads();
#pragma unroll
        for (int q = 0; q < 4; ++q) {
            unsigned k = eks[tid + q * 256];
            if (k != INF32) {
                int rlo = (int)(k & 255u), rhi = (int)(k >> 18);
                int cu = comp[rlo], cv = comp[rhi];
                if (cu != cv) {
                    atomicMin(&minE[cu], k);
                    atomicMin(&minE[cv], k);
                }
            }
        }
        __syncthreads();
        {
            unsigned mk = minE[tid];
            int o = tid;
            if (mk != INF32) {
                int rlo = (int)(mk & 255u), rhi = (int)(mk >> 18);
                int cu = comp[rlo], cv = comp[rhi];
                o = (cu == tid) ? cv : cu;
                mstflag[(mk >> 8) & 0x3FFu] = 1;
                chg = 1;
            }
            nxt[tid] = o;
        }
        __syncthreads();
        if (!chg) break;
        {
            int o = nxt[tid];
            int p = o;
            if (nxt[o] == tid && tid < o) p = tid;
            par2[tid] = p;
        }
        __syncthreads();
        for (int j = 0; j < 8; ++j) {
            int p = par2[par2[tid]];
            __syncthreads();
            par2[tid] = p;
            __syncthreads();
        }
        comp[tid] = par2[comp[tid]];
        __syncthreads();
    }

    // collect MST edges (<=255)
    if (tid == 0) cnt = 0;
    __syncthreads();
#pragma unroll
    for (int q = 0; q < 4; ++q) {
        int e = tid + q * 256;
        if (mstflag[e]) {
            int p = atomicAdd(&cnt, 1);
            mstK[p] = eks[e];
        }
    }
    __syncthreads();
    if (tid >= cnt) mstK[tid] = INF32;
    __syncthreads();

    // counting sort of MST keys (unique among valid)
    unsigned myk2 = mstK[tid];
    if (myk2 != INF32) {
        int pos = 0;
#pragma unroll 8
        for (int j = 0; j < NODES; ++j) pos += (mstK[j] < myk2) ? 1 : 0;
        srt[pos] = myk2;
    }
    __syncthreads();

    // serial Kruskal replay (rank domain: elder = smaller rank, death=fvr[rhi])
    if (tid == 0) {
        for (int s = 0; s < NODES; ++s) {
            unsigned k = srt[s];
            if (k == INF32) break;
            int rlo = (int)(k & 255u), rhi = (int)(k >> 18);
            int a = rlo; while (par[a] != a) { par[a] = par[par[a]]; a = par[a]; }
            int b = rhi; while (par[b] != b) { par[b] = par[par[b]]; b = par[b]; }
            if (a != b) {
                int elder = a < b ? a : b, young = a < b ? b : a;
                par[young] = elder;
                dr[young] = rhi;
            }
        }
    }
    __syncthreads();

    // component max (extended persistence)
    int r = tid;
    while (par[r] != r) r = par[r];
    atomicMax(&cmaxr[r], tid);
    __syncthreads();

    float dv = (dr[tid] >= 0) ? fvr[dr[tid]] : fvr[cmaxr[r]];
    dout[sgn * NTOT + g * NODES + order_[tid]] = dv;
}

// ------- Stage 3: per-pair MLPs + segment sum + linear head (fused) -------
__global__ __launch_bounds__(256) void k_head(
    const float* __restrict__ zbuf, const float* __restrict__ b2,
    const float* __restrict__ dbuf,
    const float* __restrict__ wp0, const float* __restrict__ bp0,
    const float* __restrict__ wp1, const float* __restrict__ bp1,
    const float* __restrict__ wh, const float* __restrict__ bh,
    float* __restrict__ out)
{
    const int g = blockIdx.x, tid = threadIdx.x;
    __shared__ float lf[NODES], l0[NODES], l1[NODES];
    __shared__ float sp0[NODES], sp1[NODES];
    lf[tid] = 1.f / (1.f + expf(-(zbuf[g * NODES + tid] + b2[0])));
    l0[tid] = dbuf[g * NODES + tid];
    l1[tid] = dbuf[NTOT + g * NODES + tid];
    __syncthreads();
    const float w00 = wp0[tid], w01 = wp0[HP + tid], bb0 = bp0[tid];
    const float w10 = wp1[tid], w11 = wp1[HP + tid], bb1 = bp1[tid];
    float s0 = 0.f, s1 = 0.f;
    for (int n = 0; n < NODES; ++n) {
        float f = lf[n], d0 = l0[n], d1 = l1[n];
        float a0 = fmaf(f, w00, fmaf(d0, w01, bb0));      // h0 = (f, d_sub)
        float a1 = fmaf(-d1, w10, fmaf(f, w11, bb1));     // h1 = (-d_sup, f)
        s0 += a0 > 0.f ? a0 : 0.f;
        s1 += a1 > 0.f ? a1 : 0.f;
    }
    sp0[tid] = s0; sp1[tid] = s1;
    __syncthreads();
    if (tid < NC) {
        float acc = bh[tid];
        for (int j = 0; j < HP; ++j)
            acc += sp0[j] * wh[j * NC + tid] + sp1[j] * wh[(HP + j) * NC + tid];
        out[g * NC + tid] = acc;   // f32 output (reference dtype)
    }
}

extern "C" void kernel_launch(void* const* d_in, const int* in_sizes, int n_in,
                              void* d_out, int out_size, void* d_ws, size_t ws_size,
                              hipStream_t stream)
{
    const float* x   = (const float*)d_in[0];
    const int*   edg = (const int*)d_in[1];
    const float* w1  = (const float*)d_in[3];
    const float* b1  = (const float*)d_in[4];
    const float* w2  = (const float*)d_in[5];
    const float* b2  = (const float*)d_in[6];
    const float* wp0 = (const float*)d_in[7];
    const float* bp0 = (const float*)d_in[8];
    const float* wp1 = (const float*)d_in[9];
    const float* bp1 = (const float*)d_in[10];
    const float* wh  = (const float*)d_in[11];
    const float* bh  = (const float*)d_in[12];

    float* zbuf = (float*)d_ws;                       // [NTOT] f32 (pre-sigmoid)
    float* dbuf = zbuf + NTOT;                        // [2][NTOT] f32
    unsigned short* w1f = (unsigned short*)(dbuf + 2 * NTOT);  // 1 MB bf16

    const size_t WS_REQ = (size_t)3 * NTOT * 4 + (size_t)HF * DF * 2 + 256;

    if (ws_size >= WS_REQ) {
        k_cvt_frag<<<256, 256, 0, stream>>>(w1, w1f, zbuf);
        k_fil_mfma<<<256, 256, 0, stream>>>(x, w1f, b1, w2, zbuf);
    } else {
        k_fil     <<<NTOT / TN2, 256, 0, stream>>>(x, w1, b1, w2, zbuf);
    }
    k_pers<<<NUM_GRAPHS * 2, 256, 0, stream>>>(edg, zbuf, b2, dbuf);
    k_head<<<NUM_GRAPHS, 256, 0, stream>>>(zbuf, b2, dbuf, wp0, bp0, wp1, bp1,
                                           wh, bh, (float*)d_out);
}

// Round 14
// 244.526 us; speedup vs baseline: 1.1550x; 1.0566x over previous
//
#include <hip/hip_runtime.h>
#include <hip/hip_bf16.h>

#define NUM_GRAPHS 64
#define NODES 256
#define EDGES 1024
#define NTOT (NUM_GRAPHS * NODES) /* 16384 */
#define DF 512
#define HF 1024
#define HP 256
#define NC 10
#define INF32 0xFFFFFFFFu

typedef short bf16x8 __attribute__((ext_vector_type(8)));
typedef float f32x4 __attribute__((ext_vector_type(4)));

__device__ __forceinline__ unsigned short bf16r(float f) {
    __hip_bfloat16 h = __float2bfloat16(f);
    return *(unsigned short*)&h;
}
// monotone order-preserving encode for fp32 (bijection, works for +/-)
__device__ __forceinline__ unsigned encf(float x) {
    union { float f; unsigned u; } c; c.f = x;
    return (c.u & 0x80000000u) ? ~c.u : (c.u | 0x80000000u);
}

// ---- w1 (f32 [k][j]) -> w1f bf16 in MFMA B-fragment order ----------------
// w1f elem index: ((cg*16 + t)*16 + n16)*32 + quad*8 + j, col = cg*16+n16,
// k = t*32 + quad*8 + j. 256 blocks: (cg, kq) -> 16 cols x 128 k each.
__global__ __launch_bounds__(256) void k_cvt_frag(
    const float* __restrict__ w1, unsigned short* __restrict__ w1f)
{
    __shared__ float ls[128 * 16];   // [kk][c], 8 KB
    const int tid = threadIdx.x;
    const int cg = blockIdx.x >> 2, kq = blockIdx.x & 3;
    const int c = tid & 15, kr = tid >> 4;
#pragma unroll
    for (int it = 0; it < 8; ++it) {
        int kk = it * 16 + kr;
        ls[kk * 16 + c] = w1[(size_t)(kq * 128 + kk) * HF + cg * 16 + c];
    }
    __syncthreads();
    const int tt = tid >> 6, n16 = (tid >> 2) & 15, q = tid & 3;
    unsigned short v[8];
#pragma unroll
    for (int j = 0; j < 8; ++j)
        v[j] = bf16r(ls[(tt * 32 + q * 8 + j) * 16 + n16]);
    size_t off = ((size_t)(cg * 16 + kq * 4 + tt) * 16 + n16) * 32 + q * 8;
#pragma unroll
    for (int j = 0; j < 8; ++j) w1f[off + j] = v[j];
}

// ------- Stage 1 (MFMA v4): zbuf = relu(x@W1+b1)@w2 (pre-b2/sigmoid) ------
// 256 blocks x 64 rows. Wave wv owns 16 rows (A in 64 VGPR, direct from x);
// B (w1f) double-buffered in 2x16 KB LDS shared by all 4 waves -> w1f read
// ONCE per block. 2-chain MFMA ILP. Each output row finished by one lane:
// plain store, no atomics, no pre-zero. Register budget ~115 (no spills).
__global__ __launch_bounds__(256, 2) void k_fil_mfma(
    const float* __restrict__ x, const unsigned short* __restrict__ w1f,
    const float* __restrict__ b1, const float* __restrict__ w2,
    float* __restrict__ zbuf)
{
    __shared__ unsigned short Bbuf[2][16 * 512];  // 2 x 16 KB
    const int tid = threadIdx.x;
    const int lane = tid & 63;
    const int wv = tid >> 6;            // wave 0..3 = row tile
    const int l15 = lane & 15, quad = lane >> 4;
    const int r0 = blockIdx.x * 64;
    const int row = r0 + wv * 16 + l15;

    // A fragments: row m=l15, k = t*32 + quad*8 + j ; f32 -> bf16 in regs
    bf16x8 A[16];
#pragma unroll
    for (int t = 0; t < 16; ++t) {
        const float* src = x + (size_t)row * DF + t * 32 + quad * 8;
        float4 v0 = *(const float4*)src;
        float4 v1 = *(const float4*)(src + 4);
        A[t][0] = (short)bf16r(v0.x); A[t][1] = (short)bf16r(v0.y);
        A[t][2] = (short)bf16r(v0.z); A[t][3] = (short)bf16r(v0.w);
        A[t][4] = (short)bf16r(v1.x); A[t][5] = (short)bf16r(v1.y);
        A[t][6] = (short)bf16r(v1.z); A[t][7] = (short)bf16r(v1.w);
    }

    // prime cg=0 into buf 0 (thread tid copies 64 B)
    uint4 pf0, pf1, pf2, pf3;
    {
        const uint4* s = (const uint4*)w1f;
        pf0 = s[tid * 4]; pf1 = s[tid * 4 + 1];
        pf2 = s[tid * 4 + 2]; pf3 = s[tid * 4 + 3];
        uint4* d = (uint4*)Bbuf[0];
        d[tid * 4] = pf0; d[tid * 4 + 1] = pf1;
        d[tid * 4 + 2] = pf2; d[tid * 4 + 3] = pf3;
    }
    __syncthreads();

    float s_[4] = {0.f, 0.f, 0.f, 0.f};

    for (int cg = 0; cg < 64; ++cg) {
        const int buf = cg & 1;
        if (cg < 63) {   // issue next-B loads; consumed after compute
            const uint4* s = (const uint4*)(w1f + (size_t)(cg + 1) * 8192);
            pf0 = s[tid * 4]; pf1 = s[tid * 4 + 1];
            pf2 = s[tid * 4 + 2]; pf3 = s[tid * 4 + 3];
        }
        const unsigned short* bb = &Bbuf[buf][l15 * 32 + quad * 8];
        f32x4 acc0 = {0.f,0.f,0.f,0.f}, acc1 = {0.f,0.f,0.f,0.f};
#pragma unroll
        for (int t = 0; t < 8; ++t) {
            bf16x8 Bf0 = *(const bf16x8*)(bb + t * 512);
            bf16x8 Bf1 = *(const bf16x8*)(bb + (t + 8) * 512);
            acc0 = __builtin_amdgcn_mfma_f32_16x16x32_bf16(A[t], Bf0, acc0, 0, 0, 0);
            acc1 = __builtin_amdgcn_mfma_f32_16x16x32_bf16(A[t + 8], Bf1, acc1, 0, 0, 0);
        }
        const int col = cg * 16 + l15;
        const float b1c = b1[col], w2c = w2[col];
#pragma unroll
        for (int r = 0; r < 4; ++r) {
            float h = (acc0[r] + acc1[r]) + b1c;
            h = h > 0.f ? h : 0.f;
            s_[r] = fmaf(h, w2c, s_[r]);
        }
        if (cg < 63) {
            uint4* d = (uint4*)Bbuf[buf ^ 1];
            d[tid * 4] = pf0; d[tid * 4 + 1] = pf1;
            d[tid * 4 + 2] = pf2; d[tid * 4 + 3] = pf3;
        }
        __syncthreads();
    }

    // D row = quad*4 + r; reduce over the 16 col-lanes (l15); plain store
#pragma unroll
    for (int r = 0; r < 4; ++r) {
        float v = s_[r];
        v += __shfl_xor(v, 1, 16);
        v += __shfl_xor(v, 2, 16);
        v += __shfl_xor(v, 4, 16);
        v += __shfl_xor(v, 8, 16);
        if (l15 == 0) zbuf[r0 + wv * 16 + quad * 4 + r] = v;
    }
}

// ---------------- Stage 1 legacy (fp32 VALU) — ws_size fallback -----------
#define TN2 16
__global__ __launch_bounds__(256) void k_fil(
    const float* __restrict__ x, const float* __restrict__ w1,
    const float* __restrict__ b1, const float* __restrict__ w2,
    float* __restrict__ zout)
{
    __shared__ float xs[TN2][DF];
    __shared__ float part[256];
    const int tid = threadIdx.x;
    const int n0 = blockIdx.x * TN2;
    for (int c = tid; c < TN2 * DF / 4; c += 256) {
        int n = c >> 7, k4 = (c & 127) << 2;
        *(float4*)&xs[n][k4] = *(const float4*)(x + (size_t)(n0 + n) * DF + k4);
    }
    __syncthreads();
    float h[TN2][4];
#pragma unroll
    for (int n = 0; n < TN2; ++n)
#pragma unroll
        for (int q = 0; q < 4; ++q) h[n][q] = 0.f;
    for (int k = 0; k < DF; ++k) {
        float wr[4];
#pragma unroll
        for (int q = 0; q < 4; ++q) wr[q] = w1[(size_t)k * HF + tid + 256 * q];
#pragma unroll
        for (int n = 0; n < TN2; ++n) {
            float xv = xs[n][k];
#pragma unroll
            for (int q = 0; q < 4; ++q) h[n][q] = fmaf(xv, wr[q], h[n][q]);
        }
    }
    float b1r[4], w2r[4];
#pragma unroll
    for (int q = 0; q < 4; ++q) { b1r[q] = b1[tid + 256 * q]; w2r[q] = w2[tid + 256 * q]; }
    for (int n = 0; n < TN2; ++n) {
        float s = 0.f;
#pragma unroll
        for (int q = 0; q < 4; ++q) {
            float hv = h[n][q] + b1r[q];
            s += (hv > 0.f ? hv : 0.f) * w2r[q];
        }
        part[tid] = s;
        __syncthreads();
        for (int off = 128; off > 0; off >>= 1) {
            if (tid < off) part[tid] += part[tid + off];
            __syncthreads();
        }
        if (tid == 0) zout[n0 + n] = part[0];
        __syncthreads();
    }
}

// ------------- Stage 2: Boruvka MST filter + scalar Kruskal replay --------
// f = sigmoid(z + b2) inline (monotone). Replay: comp flat in wave-0 regs
// (4 verts/lane), roots via readlane (SGPR path, no LDS latency).
__global__ __launch_bounds__(256) void k_pers(
    const int* __restrict__ edges, const float* __restrict__ zbuf,
    const float* __restrict__ b2, float* __restrict__ dout /* [2][NTOT] */)
{
    const int bid = blockIdx.x;
    const int g = bid >> 1, sgn = bid & 1;
    const int tid = threadIdx.x;

    __shared__ float fv[NODES];
    __shared__ unsigned long long vkey[NODES];
    __shared__ int order_[NODES], rank_[NODES];
    __shared__ float fvr[NODES];
    __shared__ unsigned eks[EDGES];
    __shared__ int comp[NODES];
    __shared__ unsigned minE[NODES];
    __shared__ int nxt[NODES], par2[NODES];
    __shared__ unsigned char mstflag[EDGES];
    __shared__ int cnt, chg;
    __shared__ unsigned mstK[NODES], srt[NODES];
    __shared__ int par[NODES], dr[NODES], cmaxr[NODES];

    float z0 = zbuf[g * NODES + tid];
    float f0 = 1.f / (1.f + expf(-(z0 + b2[0])));
    fv[tid] = sgn ? -f0 : f0;
    unsigned long long myk = ((unsigned long long)encf(fv[tid]) << 32) | (unsigned)tid;
    vkey[tid] = myk;
    srt[tid] = INF32; dr[tid] = -1; cmaxr[tid] = 0;
    __syncthreads();

    // counting rank (keys unique): rank = #{j : key[j] < mine}
    int rk = 0;
#pragma unroll 8
    for (int j = 0; j < NODES; ++j) rk += (vkey[j] < myk) ? 1 : 0;
    order_[rk] = tid;
    rank_[tid] = rk;
    fvr[rk] = fv[tid];
    comp[tid] = tid;
    __syncthreads();

    // edge keys in rank domain; self-loops -> INF
#pragma unroll
    for (int q = 0; q < 4; ++q) {
        int e = tid + q * 256;
        int u = edges[2 * (g * EDGES + e)]     - g * NODES;
        int v = edges[2 * (g * EDGES + e) + 1] - g * NODES;
        if (u == v) { eks[e] = INF32; }
        else {
            int ra = rank_[u], rb = rank_[v];
            int rlo = ra < rb ? ra : rb, rhi = ra < rb ? rb : ra;
            eks[e] = ((unsigned)rhi << 18) | ((unsigned)e << 8) | (unsigned)rlo;
        }
        mstflag[e] = 0;
    }
    __syncthreads();

    // Boruvka with early exit + convergence-checked pointer jumping
    for (int round = 0; round < 8; ++round) {
        minE[tid] = INF32;
        if (tid == 0) chg = 0;
        __syncthreads();
#pragma unroll
        for (int q = 0; q < 4; ++q) {
            unsigned k = eks[tid + q * 256];
            if (k != INF32) {
                int rlo = (int)(k & 255u), rhi = (int)(k >> 18);
                int cu = comp[rlo], cv = comp[rhi];
                if (cu != cv) {
                    atomicMin(&minE[cu], k);
                    atomicMin(&minE[cv], k);
                }
            }
        }
        __syncthreads();
        {
            unsigned mk = minE[tid];
            int o = tid;
            if (mk != INF32) {
                int rlo = (int)(mk & 255u), rhi = (int)(mk >> 18);
                int cu = comp[rlo], cv = comp[rhi];
                o = (cu == tid) ? cv : cu;
                mstflag[(mk >> 8) & 0x3FFu] = 1;
                chg = 1;
            }
            nxt[tid] = o;
        }
        __syncthreads();
        if (!chg) break;
        {
            int o = nxt[tid];
            int p = o;
            if (nxt[o] == tid && tid < o) p = tid;
            par2[tid] = p;
        }
        __syncthreads();
        for (;;) {
            int p = par2[par2[tid]];
            int done = __syncthreads_and(p == par2[tid]);
            if (done) break;
            par2[tid] = p;
            __syncthreads();
        }
        comp[tid] = par2[comp[tid]];
        __syncthreads();
    }

    // collect MST edges (<=255)
    if (tid == 0) cnt = 0;
    __syncthreads();
#pragma unroll
    for (int q = 0; q < 4; ++q) {
        int e = tid + q * 256;
        if (mstflag[e]) {
            int p = atomicAdd(&cnt, 1);
            mstK[p] = eks[e];
        }
    }
    __syncthreads();
    if (tid >= cnt) mstK[tid] = INF32;
    __syncthreads();

    // counting sort of MST keys (unique among valid)
    unsigned myk2 = mstK[tid];
    if (myk2 != INF32) {
        int pos = 0;
#pragma unroll 8
        for (int j = 0; j < NODES; ++j) pos += (mstK[j] < myk2) ? 1 : 0;
        srt[pos] = myk2;
    }
    __syncthreads();

    // scalar-engine Kruskal replay on wave 0: comp flat in registers
    // (lane L holds ranks 4L..4L+3); uniform scalar flow via readlane.
    if (tid < 64) {
        int c0 = tid * 4, c1 = tid * 4 + 1, c2 = tid * 4 + 2, c3 = tid * 4 + 3;
        unsigned kA = srt[tid], kB = srt[64 + tid],
                 kC = srt[128 + tid], kD = srt[192 + tid];
        const int CNT = cnt;
        for (int s = 0; s < CNT; ++s) {
            int slot = s >> 6, sl = s & 63;
            unsigned kk;
            if (slot == 0)      kk = (unsigned)__builtin_amdgcn_readlane((int)kA, sl);
            else if (slot == 1) kk = (unsigned)__builtin_amdgcn_readlane((int)kB, sl);
            else if (slot == 2) kk = (unsigned)__builtin_amdgcn_readlane((int)kC, sl);
            else                kk = (unsigned)__builtin_amdgcn_readlane((int)kD, sl);
            int rlo = (int)(kk & 255u), rhi = (int)(kk >> 18);
            int la = rlo >> 2, sa = rlo & 3;
            int av;
            if (sa == 0)      av = __builtin_amdgcn_readlane(c0, la);
            else if (sa == 1) av = __builtin_amdgcn_readlane(c1, la);
            else if (sa == 2) av = __builtin_amdgcn_readlane(c2, la);
            else              av = __builtin_amdgcn_readlane(c3, la);
            int lb = rhi >> 2, sb = rhi & 3;
            int bv;
            if (sb == 0)      bv = __builtin_amdgcn_readlane(c0, lb);
            else if (sb == 1) bv = __builtin_amdgcn_readlane(c1, lb);
            else if (sb == 2) bv = __builtin_amdgcn_readlane(c2, lb);
            else              bv = __builtin_amdgcn_readlane(c3, lb);
            if (av != bv) {
                int elder = av < bv ? av : bv;
                int young = av < bv ? bv : av;
                c0 = (c0 == young) ? elder : c0;
                c1 = (c1 == young) ? elder : c1;
                c2 = (c2 == young) ? elder : c2;
                c3 = (c3 == young) ? elder : c3;
                if (tid == 0) dr[young] = rhi;
            }
        }
        par[tid * 4] = c0; par[tid * 4 + 1] = c1;
        par[tid * 4 + 2] = c2; par[tid * 4 + 3] = c3;
    }
    __syncthreads();

    // component max (extended persistence); par is flat
    int r = par[tid];
    atomicMax(&cmaxr[r], tid);
    __syncthreads();

    float dv = (dr[tid] >= 0) ? fvr[dr[tid]] : fvr[cmaxr[r]];
    dout[sgn * NTOT + g * NODES + order_[tid]] = dv;
}

// ------- Stage 3: per-pair MLPs + segment sum + linear head (fused) -------
__global__ __launch_bounds__(256) void k_head(
    const float* __restrict__ zbuf, const float* __restrict__ b2,
    const float* __restrict__ dbuf,
    const float* __restrict__ wp0, const float* __restrict__ bp0,
    const float* __restrict__ wp1, const float* __restrict__ bp1,
    const float* __restrict__ wh, const float* __restrict__ bh,
    float* __restrict__ out)
{
    const int g = blockIdx.x, tid = threadIdx.x;
    __shared__ float lf[NODES], l0[NODES], l1[NODES];
    __shared__ float sp0[NODES], sp1[NODES];
    lf[tid] = 1.f / (1.f + expf(-(zbuf[g * NODES + tid] + b2[0])));
    l0[tid] = dbuf[g * NODES + tid];
    l1[tid] = dbuf[NTOT + g * NODES + tid];
    __syncthreads();
    const float w00 = wp0[tid], w01 = wp0[HP + tid], bb0 = bp0[tid];
    const float w10 = wp1[tid], w11 = wp1[HP + tid], bb1 = bp1[tid];
    float s0 = 0.f, s1 = 0.f;
    for (int n = 0; n < NODES; ++n) {
        float f = lf[n], d0 = l0[n], d1 = l1[n];
        float a0 = fmaf(f, w00, fmaf(d0, w01, bb0));      // h0 = (f, d_sub)
        float a1 = fmaf(-d1, w10, fmaf(f, w11, bb1));     // h1 = (-d_sup, f)
        s0 += a0 > 0.f ? a0 : 0.f;
        s1 += a1 > 0.f ? a1 : 0.f;
    }
    sp0[tid] = s0; sp1[tid] = s1;
    __syncthreads();
    if (tid < NC) {
        float acc = bh[tid];
        for (int j = 0; j < HP; ++j)
            acc += sp0[j] * wh[j * NC + tid] + sp1[j] * wh[(HP + j) * NC + tid];
        out[g * NC + tid] = acc;   // f32 output (reference dtype)
    }
}

extern "C" void kernel_launch(void* const* d_in, const int* in_sizes, int n_in,
                              void* d_out, int out_size, void* d_ws, size_t ws_size,
                              hipStream_t stream)
{
    const float* x   = (const float*)d_in[0];
    const int*   edg = (const int*)d_in[1];
    const float* w1  = (const float*)d_in[3];
    const float* b1  = (const float*)d_in[4];
    const float* w2  = (const float*)d_in[5];
    const float* b2  = (const float*)d_in[6];
    const float* wp0 = (const float*)d_in[7];
    const float* bp0 = (const float*)d_in[8];
    const float* wp1 = (const float*)d_in[9];
    const float* bp1 = (const float*)d_in[10];
    const float* wh  = (const float*)d_in[11];
    const float* bh  = (const float*)d_in[12];

    float* zbuf = (float*)d_ws;                       // [NTOT] f32 (pre-sigmoid)
    float* dbuf = zbuf + NTOT;                        // [2][NTOT] f32
    unsigned short* w1f = (unsigned short*)(dbuf + 2 * NTOT);  // 1 MB bf16

    const size_t WS_REQ = (size_t)3 * NTOT * 4 + (size_t)HF * DF * 2 + 256;

    if (ws_size >= WS_REQ) {
        k_cvt_frag<<<256, 256, 0, stream>>>(w1, w1f);
        k_fil_mfma<<<256, 256, 0, stream>>>(x, w1f, b1, w2, zbuf);
    } else {
        k_fil     <<<NTOT / TN2, 256, 0, stream>>>(x, w1, b1, w2, zbuf);
    }
    k_pers<<<NUM_GRAPHS * 2, 256, 0, stream>>>(edg, zbuf, b2, dbuf);
    k_head<<<NUM_GRAPHS, 256, 0, stream>>>(zbuf, b2, dbuf, wp0, bp0, wp1, bp1,
                                           wh, bh, (float*)d_out);
}